// Round 1
// baseline (415.108 us; speedup 1.0000x reference)
//
#include <hip/hip_runtime.h>

typedef unsigned short u16;
typedef __attribute__((ext_vector_type(8))) short bf16x8;
typedef __attribute__((ext_vector_type(4))) float f32x4;

// ---------- bf16 split helpers ----------
__device__ __forceinline__ u16 f2bf_rne(float f) {
  unsigned u = __float_as_uint(f);
  u += 0x7fffu + ((u >> 16) & 1u);
  return (u16)(u >> 16);
}
__device__ __forceinline__ float bf2f(u16 h) {
  return __uint_as_float(((unsigned)h) << 16);
}
__device__ __forceinline__ void split1(float v, u16& h, u16& l) {
  u16 hh = f2bf_rne(v);
  h = hh;
  l = f2bf_rne(v - bf2f(hh));
}

// ---------- global -> LDS async 16B ----------
__device__ __forceinline__ void gl16(const void* g, void* l) {
  __builtin_amdgcn_global_load_lds(
      (const __attribute__((address_space(1))) unsigned int*)g,
      (__attribute__((address_space(3))) unsigned int*)l,
      16, 0, 0);
}

// ---------- elementwise split-convert (vec4) ----------
__global__ void split_convert4(const float4* __restrict__ in,
                               ushort4* __restrict__ hi, ushort4* __restrict__ lo, int n4) {
  int i = blockIdx.x * 256 + threadIdx.x;
  if (i >= n4) return;
  float4 v = in[i];
  ushort4 h, l;
  split1(v.x, h.x, l.x); split1(v.y, h.y, l.y);
  split1(v.z, h.z, l.z); split1(v.w, h.w, l.w);
  hi[i] = h; lo[i] = l;
}

// ---------- split-bf16 GEMM: C[M,N] = A[M,K] * B[N,K]^T (both K-major) ----------
// 128x128 tile, BK=32, 4 waves (2x2), each wave 64x64 via 4x4 mfma_f32_16x16x32_bf16.
// 3 MFMAs per fragment pair: hi*hi + hi*lo + lo*hi  (~2^-17 product error).
__global__ __launch_bounds__(256, 2) void gemm_split_bt(
    const u16* __restrict__ Ahi, const u16* __restrict__ Alo,
    const u16* __restrict__ Bhi, const u16* __restrict__ Blo,
    float* __restrict__ C, int M, int N, int K) {
  __shared__ __align__(16) u16 sAh[128 * 32], sAl[128 * 32], sBh[128 * 32], sBl[128 * 32];
  const int tid = threadIdx.x;
  const int wave = tid >> 6;
  const int lane = tid & 63;
  const int tm0 = blockIdx.x * 128;
  const int tn0 = blockIdx.y * 128;
  const int wm = (wave & 1) * 64;
  const int wn = (wave >> 1) * 64;

  // staging: per wave 2 global_load_lds per array, each covers 16 rows (64B/row, 4 lanes/row)
  const int srow = wave * 32 + (lane >> 2);
  const int scol = (lane & 3) * 8;
  const u16* gAh = Ahi + (size_t)(tm0 + srow) * K + scol;
  const u16* gAl = Alo + (size_t)(tm0 + srow) * K + scol;
  const u16* gBh = Bhi + (size_t)(tn0 + srow) * K + scol;
  const u16* gBl = Blo + (size_t)(tn0 + srow) * K + scol;
  u16* lAh = &sAh[wave * 32 * 32];
  u16* lAl = &sAl[wave * 32 * 32];
  u16* lBh = &sBh[wave * 32 * 32];
  u16* lBl = &sBl[wave * 32 * 32];
  const size_t rstep = (size_t)16 * K;

  f32x4 acc[4][4] = {};
  const int fr = lane & 15;          // A/B fragment row (m or n within 16-tile)
  const int k0 = (lane >> 4) * 8;    // k offset per quad

  for (int kt = 0; kt < K; kt += 32) {
    gl16(gAh + kt, lAh);
    gl16(gAh + kt + rstep, lAh + 16 * 32);
    gl16(gAl + kt, lAl);
    gl16(gAl + kt + rstep, lAl + 16 * 32);
    gl16(gBh + kt, lBh);
    gl16(gBh + kt + rstep, lBh + 16 * 32);
    gl16(gBl + kt, lBl);
    gl16(gBl + kt + rstep, lBl + 16 * 32);
    __syncthreads();
    bf16x8 ah[4], al[4], bh[4], bl[4];
#pragma unroll
    for (int i = 0; i < 4; ++i) {
      ah[i] = *(const bf16x8*)&sAh[(wm + i * 16 + fr) * 32 + k0];
      al[i] = *(const bf16x8*)&sAl[(wm + i * 16 + fr) * 32 + k0];
      bh[i] = *(const bf16x8*)&sBh[(wn + i * 16 + fr) * 32 + k0];
      bl[i] = *(const bf16x8*)&sBl[(wn + i * 16 + fr) * 32 + k0];
    }
#pragma unroll
    for (int i = 0; i < 4; ++i)
#pragma unroll
      for (int j = 0; j < 4; ++j) {
        acc[i][j] = __builtin_amdgcn_mfma_f32_16x16x32_bf16(ah[i], bh[j], acc[i][j], 0, 0, 0);
        acc[i][j] = __builtin_amdgcn_mfma_f32_16x16x32_bf16(ah[i], bl[j], acc[i][j], 0, 0, 0);
        acc[i][j] = __builtin_amdgcn_mfma_f32_16x16x32_bf16(al[i], bh[j], acc[i][j], 0, 0, 0);
      }
    __syncthreads();
  }

  // C/D layout: col = lane&15, row = (lane>>4)*4 + reg  (verified m89/m91)
  const int col = lane & 15;
  const int rowq = (lane >> 4) * 4;
#pragma unroll
  for (int i = 0; i < 4; ++i)
#pragma unroll
    for (int j = 0; j < 4; ++j) {
      size_t base = (size_t)(tm0 + wm + i * 16 + rowq) * N + (tn0 + wn + j * 16 + col);
#pragma unroll
      for (int r = 0; r < 4; ++r) C[base + (size_t)r * N] = acc[i][j][r];
    }
}

// ---------- fused dilated attention ----------
// One block per (b, i0): tokens T_j = i0 + 2048*j, j=0..3. All 3 branches fold into
// a 4x4 combination matrix A per head: r=1 full softmax4; r=2 (i0 even) pair softmax2
// on (j, j^2); r=4 (i0%4==0) += identity.
__global__ __launch_bounds__(256) void attn_dilated(const float* __restrict__ qkv,
                                                    float* __restrict__ out) {
  __shared__ float rows[4][2304];   // [3][12][64] per token
  __shared__ float sc[12][16];
  __shared__ float Aw[12][16];
  const int t = threadIdx.x;
  const int i0 = blockIdx.x;  // 0..2047
  const int b = blockIdx.y;   // 0..1
  const size_t rowbase = (size_t)b * 8192 + i0;

  for (int idx = t; idx < 4 * 576; idx += 256) {
    int j = idx / 576, c4 = idx - j * 576;
    ((float4*)rows[j])[c4] = ((const float4*)(qkv + (rowbase + 2048 * j) * 2304))[c4];
  }
  __syncthreads();

  if (t < 192) {  // scores: q_j . k_jp / 8
    int h = t >> 4, j = (t >> 2) & 3, jp = t & 3;
    const float* q = &rows[j][h * 64];
    const float* k = &rows[jp][768 + h * 64];
    float s = 0.f;
#pragma unroll
    for (int d = 0; d < 64; ++d) s = fmaf(q[d], k[d], s);
    sc[h][(j << 2) | jp] = s * 0.125f;
  }
  __syncthreads();

  if (t < 48) {  // combine branch weights
    int h = t >> 2, j = t & 3;
    float s0 = sc[h][j * 4 + 0], s1 = sc[h][j * 4 + 1];
    float s2 = sc[h][j * 4 + 2], s3 = sc[h][j * 4 + 3];
    float m = fmaxf(fmaxf(s0, s1), fmaxf(s2, s3));
    float e0 = expf(s0 - m), e1 = expf(s1 - m), e2 = expf(s2 - m), e3 = expf(s3 - m);
    float inv = 1.f / (e0 + e1 + e2 + e3);
    float a[4] = {e0 * inv, e1 * inv, e2 * inv, e3 * inv};
    if ((i0 & 1) == 0) {
      int p = j ^ 2;
      float ss = sc[h][j * 4 + j], sx = sc[h][j * 4 + p];
      float mm = fmaxf(ss, sx);
      float es = expf(ss - mm), ex = expf(sx - mm);
      float iv = 1.f / (es + ex);
      a[j] += es * iv;
      a[p] += ex * iv;
    }
    if ((i0 & 3) == 0) a[j] += 1.f;
    Aw[h][j * 4 + 0] = a[0]; Aw[h][j * 4 + 1] = a[1];
    Aw[h][j * 4 + 2] = a[2]; Aw[h][j * 4 + 3] = a[3];
  }
  __syncthreads();

#pragma unroll
  for (int j = 0; j < 4; ++j) {
#pragma unroll
    for (int rep = 0; rep < 3; ++rep) {
      int c = rep * 256 + t;  // 0..767
      int h = c >> 6;
      float v = 0.f;
#pragma unroll
      for (int jp = 0; jp < 4; ++jp) v = fmaf(Aw[h][(j << 2) | jp], rows[jp][1536 + c], v);
      out[(rowbase + 2048 * j) * 768 + c] = v;
    }
  }
}

// ---------- column sums S[b,c] = sum_p out[b,p,c] ----------
__global__ void colsum(const float* __restrict__ o, float* __restrict__ S) {
  int t = threadIdx.x;
  int rg = blockIdx.x;  // 0..63 (128 rows each)
  int cg = blockIdx.y;  // 0..2
  int b = blockIdx.z;   // 0..1
  int c = cg * 256 + t;
  const float* p = o + ((size_t)b * 8192 + (size_t)rg * 128) * 768 + c;
  float s = 0.f;
  for (int r = 0; r < 128; ++r) s += p[(size_t)r * 768];
  atomicAdd(&S[b * 768 + c], s);
}

__global__ void invk(float* S, int n) {
  int i = blockIdx.x * 256 + threadIdx.x;
  if (i < n) S[i] = 1.0f / S[i];
}

// ---------- normalize by S and split-convert ----------
__global__ void norm_split4(const float4* __restrict__ in, const float* __restrict__ Sinv,
                            ushort4* __restrict__ hi, ushort4* __restrict__ lo, int n4) {
  int i = blockIdx.x * 256 + threadIdx.x;
  if (i >= n4) return;
  int e = i * 4;
  int c = e % 768;
  int b = e / (8192 * 768);
  const float* s = Sinv + b * 768 + c;
  float4 v = in[i];
  v.x *= s[0]; v.y *= s[1]; v.z *= s[2]; v.w *= s[3];
  ushort4 h, l;
  split1(v.x, h.x, l.x); split1(v.y, h.y, l.y);
  split1(v.z, h.z, l.z); split1(v.w, h.w, l.w);
  hi[i] = h; lo[i] = l;
}

extern "C" void kernel_launch(void* const* d_in, const int* in_sizes, int n_in,
                              void* d_out, int out_size, void* d_ws, size_t ws_size,
                              hipStream_t stream) {
  (void)in_sizes; (void)n_in; (void)out_size; (void)ws_size;
  const float* x = (const float*)d_in[0];     // (2,8192,768)
  const float* Wqkv = (const float*)d_in[1];  // (2304,768)
  const float* Wout = (const float*)d_in[2];  // (768,768)
  float* out = (float*)d_out;                 // (2,8192,768) fp32; also attn scratch

  // workspace layout (bytes). qkv region is reused for no_hi/no_lo after attention.
  char* w = (char*)d_ws;
  float* qkv = (float*)(w);                    // 150,994,944
  u16* no_hi = (u16*)(w);                      // 25,165,824 (reuse)
  u16* no_lo = (u16*)(w + 25165824);           // 25,165,824 (reuse)
  size_t off = 150994944;
  u16* xhi = (u16*)(w + off); off += 25165824;
  u16* xlo = (u16*)(w + off); off += 25165824;
  u16* wqh = (u16*)(w + off); off += 3538944;
  u16* wql = (u16*)(w + off); off += 3538944;
  u16* woh = (u16*)(w + off); off += 1179648;
  u16* wol = (u16*)(w + off); off += 1179648;
  float* S = (float*)(w + off); off += 6144;   // ~201 MB total

  // 1) split-convert inputs
  split_convert4<<<dim3((12582912 / 4 + 255) / 256), 256, 0, stream>>>(
      (const float4*)x, (ushort4*)xhi, (ushort4*)xlo, 12582912 / 4);
  split_convert4<<<dim3((1769472 / 4 + 255) / 256), 256, 0, stream>>>(
      (const float4*)Wqkv, (ushort4*)wqh, (ushort4*)wql, 1769472 / 4);
  split_convert4<<<dim3((589824 / 4 + 255) / 256), 256, 0, stream>>>(
      (const float4*)Wout, (ushort4*)woh, (ushort4*)wol, 589824 / 4);

  // 2) qkv = x @ Wqkv^T   (M=16384, N=2304, K=768)
  gemm_split_bt<<<dim3(128, 18), 256, 0, stream>>>(xhi, xlo, wqh, wql, qkv, 16384, 2304, 768);

  // 3) dilated attention -> out (d_out as scratch)
  attn_dilated<<<dim3(2048, 2), 256, 0, stream>>>(qkv, out);

  // 4) S = column sums over n; then invert
  hipMemsetAsync(S, 0, 6144, stream);
  colsum<<<dim3(64, 3, 2), 256, 0, stream>>>(out, S);
  invk<<<dim3(6), 256, 0, stream>>>(S, 1536);

  // 5) normalize + split-convert (reuses qkv region)
  norm_split4<<<dim3((3145728 + 255) / 256), 256, 0, stream>>>(
      (const float4*)out, S, (ushort4*)no_hi, (ushort4*)no_lo, 3145728);

  // 6) out = no @ Wout^T   (M=16384, N=768, K=768)
  gemm_split_bt<<<dim3(128, 6), 256, 0, stream>>>(no_hi, no_lo, woh, wol, out, 16384, 768, 768);
}

// Round 2
// 410.540 us; speedup vs baseline: 1.0111x; 1.0111x over previous
//
#include <hip/hip_runtime.h>

typedef unsigned short u16;
typedef __attribute__((ext_vector_type(8))) short bf16x8;
typedef __attribute__((ext_vector_type(4))) float f32x4;

// ---------- bf16 split helpers ----------
__device__ __forceinline__ u16 f2bf_rne(float f) {
  unsigned u = __float_as_uint(f);
  u += 0x7fffu + ((u >> 16) & 1u);
  return (u16)(u >> 16);
}
__device__ __forceinline__ float bf2f(u16 h) {
  return __uint_as_float(((unsigned)h) << 16);
}
__device__ __forceinline__ void split1(float v, u16& h, u16& l) {
  u16 hh = f2bf_rne(v);
  h = hh;
  l = f2bf_rne(v - bf2f(hh));
}

// ---------- global -> LDS async 16B ----------
__device__ __forceinline__ void gl16(const void* g, void* l) {
  __builtin_amdgcn_global_load_lds(
      (const __attribute__((address_space(1))) unsigned int*)g,
      (__attribute__((address_space(3))) unsigned int*)l,
      16, 0, 0);
}

// ---------- elementwise split-convert (vec4) ----------
__global__ void split_convert4(const float4* __restrict__ in,
                               ushort4* __restrict__ hi, ushort4* __restrict__ lo, int n4) {
  int i = blockIdx.x * 256 + threadIdx.x;
  if (i >= n4) return;
  float4 v = in[i];
  ushort4 h, l;
  split1(v.x, h.x, l.x); split1(v.y, h.y, l.y);
  split1(v.z, h.z, l.z); split1(v.w, h.w, l.w);
  hi[i] = h; lo[i] = l;
}

// ---------- split-bf16 GEMM: C[M,N] = A[M,K] * B[N,K]^T (both K-major) ----------
// 128x128 tile, BK=32, 4 waves (2x2), each wave 64x64 via 4x4 mfma_f32_16x16x32_bf16.
// 3 MFMAs per fragment pair: hi*hi + hi*lo + lo*hi  (~2^-17 product error).
// LDS XOR swizzle: 16B chunk at physical position p of row r holds logical chunk
// p ^ ((r>>1)&3). Staging loads the swizzled global column; reader XORs back.
// This spreads each 16-lane phase of ds_read_b128 across all 8 bank-groups
// (was: 2 groups -> 8-way conflict, 4 extra cyc/read measured in R1).
__global__ __launch_bounds__(256, 2) void gemm_split_bt(
    const u16* __restrict__ Ahi, const u16* __restrict__ Alo,
    const u16* __restrict__ Bhi, const u16* __restrict__ Blo,
    float* __restrict__ C, int M, int N, int K) {
  __shared__ __align__(16) u16 sAh[128 * 32], sAl[128 * 32], sBh[128 * 32], sBl[128 * 32];
  const int tid = threadIdx.x;
  const int wave = tid >> 6;
  const int lane = tid & 63;
  const int tm0 = blockIdx.x * 128;
  const int tn0 = blockIdx.y * 128;
  const int wm = (wave & 1) * 64;
  const int wn = (wave >> 1) * 64;

  // staging: per wave 2 global_load_lds per array, each covers 16 rows (64B/row, 4 lanes/row)
  const int srow = wave * 32 + (lane >> 2);
  const int c = lane & 3;
  const int scol = (c ^ ((srow >> 1) & 3)) * 8;  // XOR-swizzled source chunk
  const u16* gAh = Ahi + (size_t)(tm0 + srow) * K + scol;
  const u16* gAl = Alo + (size_t)(tm0 + srow) * K + scol;
  const u16* gBh = Bhi + (size_t)(tn0 + srow) * K + scol;
  const u16* gBl = Blo + (size_t)(tn0 + srow) * K + scol;
  u16* lAh = &sAh[wave * 32 * 32];
  u16* lAl = &sAl[wave * 32 * 32];
  u16* lBh = &sBh[wave * 32 * 32];
  u16* lBl = &sBl[wave * 32 * 32];
  const size_t rstep = (size_t)16 * K;

  f32x4 acc[4][4] = {};
  const int fr = lane & 15;            // A/B fragment row (m or n within 16-tile)
  const int quad = lane >> 4;          // logical k-chunk
  const int p = quad ^ ((fr >> 1) & 3);  // physical chunk after swizzle
  const int k0 = p * 8;                // u16 offset within row

  for (int kt = 0; kt < K; kt += 32) {
    gl16(gAh + kt, lAh);
    gl16(gAh + kt + rstep, lAh + 16 * 32);
    gl16(gAl + kt, lAl);
    gl16(gAl + kt + rstep, lAl + 16 * 32);
    gl16(gBh + kt, lBh);
    gl16(gBh + kt + rstep, lBh + 16 * 32);
    gl16(gBl + kt, lBl);
    gl16(gBl + kt + rstep, lBl + 16 * 32);
    __syncthreads();
    bf16x8 ah[4], al[4], bh[4], bl[4];
#pragma unroll
    for (int i = 0; i < 4; ++i) {
      ah[i] = *(const bf16x8*)&sAh[(wm + i * 16 + fr) * 32 + k0];
      al[i] = *(const bf16x8*)&sAl[(wm + i * 16 + fr) * 32 + k0];
      bh[i] = *(const bf16x8*)&sBh[(wn + i * 16 + fr) * 32 + k0];
      bl[i] = *(const bf16x8*)&sBl[(wn + i * 16 + fr) * 32 + k0];
    }
#pragma unroll
    for (int i = 0; i < 4; ++i)
#pragma unroll
      for (int j = 0; j < 4; ++j) {
        acc[i][j] = __builtin_amdgcn_mfma_f32_16x16x32_bf16(ah[i], bh[j], acc[i][j], 0, 0, 0);
        acc[i][j] = __builtin_amdgcn_mfma_f32_16x16x32_bf16(ah[i], bl[j], acc[i][j], 0, 0, 0);
        acc[i][j] = __builtin_amdgcn_mfma_f32_16x16x32_bf16(al[i], bh[j], acc[i][j], 0, 0, 0);
      }
    __syncthreads();
  }

  // C/D layout: col = lane&15, row = (lane>>4)*4 + reg  (verified m89/m91)
  const int col = lane & 15;
  const int rowq = (lane >> 4) * 4;
#pragma unroll
  for (int i = 0; i < 4; ++i)
#pragma unroll
    for (int j = 0; j < 4; ++j) {
      size_t base = (size_t)(tm0 + wm + i * 16 + rowq) * N + (tn0 + wn + j * 16 + col);
#pragma unroll
      for (int r = 0; r < 4; ++r) C[base + (size_t)r * N] = acc[i][j][r];
    }
}

// ---------- fused dilated attention ----------
// One block per (b, i0): tokens T_j = i0 + 2048*j, j=0..3. All 3 branches fold into
// a 4x4 combination matrix A per head: r=1 full softmax4; r=2 (i0 even) pair softmax2
// on (j, j^2); r=4 (i0%4==0) += identity.
__global__ __launch_bounds__(256) void attn_dilated(const float* __restrict__ qkv,
                                                    float* __restrict__ out) {
  __shared__ float rows[4][2304];   // [3][12][64] per token
  __shared__ float sc[12][16];
  __shared__ float Aw[12][16];
  const int t = threadIdx.x;
  const int i0 = blockIdx.x;  // 0..2047
  const int b = blockIdx.y;   // 0..1
  const size_t rowbase = (size_t)b * 8192 + i0;

  for (int idx = t; idx < 4 * 576; idx += 256) {
    int j = idx / 576, c4 = idx - j * 576;
    ((float4*)rows[j])[c4] = ((const float4*)(qkv + (rowbase + 2048 * j) * 2304))[c4];
  }
  __syncthreads();

  if (t < 192) {  // scores: q_j . k_jp / 8
    int h = t >> 4, j = (t >> 2) & 3, jp = t & 3;
    const float* q = &rows[j][h * 64];
    const float* k = &rows[jp][768 + h * 64];
    float s = 0.f;
#pragma unroll
    for (int d = 0; d < 64; ++d) s = fmaf(q[d], k[d], s);
    sc[h][(j << 2) | jp] = s * 0.125f;
  }
  __syncthreads();

  if (t < 48) {  // combine branch weights
    int h = t >> 2, j = t & 3;
    float s0 = sc[h][j * 4 + 0], s1 = sc[h][j * 4 + 1];
    float s2 = sc[h][j * 4 + 2], s3 = sc[h][j * 4 + 3];
    float m = fmaxf(fmaxf(s0, s1), fmaxf(s2, s3));
    float e0 = expf(s0 - m), e1 = expf(s1 - m), e2 = expf(s2 - m), e3 = expf(s3 - m);
    float inv = 1.f / (e0 + e1 + e2 + e3);
    float a[4] = {e0 * inv, e1 * inv, e2 * inv, e3 * inv};
    if ((i0 & 1) == 0) {
      int p = j ^ 2;
      float ss = sc[h][j * 4 + j], sx = sc[h][j * 4 + p];
      float mm = fmaxf(ss, sx);
      float es = expf(ss - mm), ex = expf(sx - mm);
      float iv = 1.f / (es + ex);
      a[j] += es * iv;
      a[p] += ex * iv;
    }
    if ((i0 & 3) == 0) a[j] += 1.f;
    Aw[h][j * 4 + 0] = a[0]; Aw[h][j * 4 + 1] = a[1];
    Aw[h][j * 4 + 2] = a[2]; Aw[h][j * 4 + 3] = a[3];
  }
  __syncthreads();

#pragma unroll
  for (int j = 0; j < 4; ++j) {
#pragma unroll
    for (int rep = 0; rep < 3; ++rep) {
      int cc = rep * 256 + t;  // 0..767
      int h = cc >> 6;
      float v = 0.f;
#pragma unroll
      for (int jp = 0; jp < 4; ++jp) v = fmaf(Aw[h][(j << 2) | jp], rows[jp][1536 + cc], v);
      out[(rowbase + 2048 * j) * 768 + cc] = v;
    }
  }
}

// ---------- column sums S[b,c] = sum_p out[b,p,c] ----------
__global__ void colsum(const float* __restrict__ o, float* __restrict__ S) {
  int t = threadIdx.x;
  int rg = blockIdx.x;  // 0..63 (128 rows each)
  int cg = blockIdx.y;  // 0..2
  int b = blockIdx.z;   // 0..1
  int c = cg * 256 + t;
  const float* p = o + ((size_t)b * 8192 + (size_t)rg * 128) * 768 + c;
  float s = 0.f;
  for (int r = 0; r < 128; ++r) s += p[(size_t)r * 768];
  atomicAdd(&S[b * 768 + c], s);
}

__global__ void invk(float* S, int n) {
  int i = blockIdx.x * 256 + threadIdx.x;
  if (i < n) S[i] = 1.0f / S[i];
}

// ---------- normalize by S and split-convert ----------
__global__ void norm_split4(const float4* __restrict__ in, const float* __restrict__ Sinv,
                            ushort4* __restrict__ hi, ushort4* __restrict__ lo, int n4) {
  int i = blockIdx.x * 256 + threadIdx.x;
  if (i >= n4) return;
  int e = i * 4;
  int c = e % 768;
  int b = e / (8192 * 768);
  const float* s = Sinv + b * 768 + c;
  float4 v = in[i];
  v.x *= s[0]; v.y *= s[1]; v.z *= s[2]; v.w *= s[3];
  ushort4 h, l;
  split1(v.x, h.x, l.x); split1(v.y, h.y, l.y);
  split1(v.z, h.z, l.z); split1(v.w, h.w, l.w);
  hi[i] = h; lo[i] = l;
}

extern "C" void kernel_launch(void* const* d_in, const int* in_sizes, int n_in,
                              void* d_out, int out_size, void* d_ws, size_t ws_size,
                              hipStream_t stream) {
  (void)in_sizes; (void)n_in; (void)out_size; (void)ws_size;
  const float* x = (const float*)d_in[0];     // (2,8192,768)
  const float* Wqkv = (const float*)d_in[1];  // (2304,768)
  const float* Wout = (const float*)d_in[2];  // (768,768)
  float* out = (float*)d_out;                 // (2,8192,768) fp32; also attn scratch

  // workspace layout (bytes). qkv region is reused for no_hi/no_lo after attention.
  char* w = (char*)d_ws;
  float* qkv = (float*)(w);                    // 150,994,944
  u16* no_hi = (u16*)(w);                      // 25,165,824 (reuse)
  u16* no_lo = (u16*)(w + 25165824);           // 25,165,824 (reuse)
  size_t off = 150994944;
  u16* xhi = (u16*)(w + off); off += 25165824;
  u16* xlo = (u16*)(w + off); off += 25165824;
  u16* wqh = (u16*)(w + off); off += 3538944;
  u16* wql = (u16*)(w + off); off += 3538944;
  u16* woh = (u16*)(w + off); off += 1179648;
  u16* wol = (u16*)(w + off); off += 1179648;
  float* S = (float*)(w + off); off += 6144;   // ~201 MB total

  // 1) split-convert inputs
  split_convert4<<<dim3((12582912 / 4 + 255) / 256), 256, 0, stream>>>(
      (const float4*)x, (ushort4*)xhi, (ushort4*)xlo, 12582912 / 4);
  split_convert4<<<dim3((1769472 / 4 + 255) / 256), 256, 0, stream>>>(
      (const float4*)Wqkv, (ushort4*)wqh, (ushort4*)wql, 1769472 / 4);
  split_convert4<<<dim3((589824 / 4 + 255) / 256), 256, 0, stream>>>(
      (const float4*)Wout, (ushort4*)woh, (ushort4*)wol, 589824 / 4);

  // 2) qkv = x @ Wqkv^T   (M=16384, N=2304, K=768)
  gemm_split_bt<<<dim3(128, 18), 256, 0, stream>>>(xhi, xlo, wqh, wql, qkv, 16384, 2304, 768);

  // 3) dilated attention -> out (d_out as scratch)
  attn_dilated<<<dim3(2048, 2), 256, 0, stream>>>(qkv, out);

  // 4) S = column sums over n; then invert
  hipMemsetAsync(S, 0, 6144, stream);
  colsum<<<dim3(64, 3, 2), 256, 0, stream>>>(out, S);
  invk<<<dim3(6), 256, 0, stream>>>(S, 1536);

  // 5) normalize + split-convert (reuses qkv region)
  norm_split4<<<dim3((3145728 + 255) / 256), 256, 0, stream>>>(
      (const float4*)out, S, (ushort4*)no_hi, (ushort4*)no_lo, 3145728);

  // 6) out = no @ Wout^T   (M=16384, N=768, K=768)
  gemm_split_bt<<<dim3(128, 6), 256, 0, stream>>>(no_hi, no_lo, woh, wol, out, 16384, 768, 768);
}

// Round 3
// 381.128 us; speedup vs baseline: 1.0892x; 1.0772x over previous
//
#include <hip/hip_runtime.h>

typedef unsigned short u16;
typedef __attribute__((ext_vector_type(8))) short bf16x8;
typedef __attribute__((ext_vector_type(4))) float f32x4;

// ---------- bf16 split helpers ----------
__device__ __forceinline__ u16 f2bf_rne(float f) {
  unsigned u = __float_as_uint(f);
  u += 0x7fffu + ((u >> 16) & 1u);
  return (u16)(u >> 16);
}
__device__ __forceinline__ float bf2f(u16 h) {
  return __uint_as_float(((unsigned)h) << 16);
}
__device__ __forceinline__ void split1(float v, u16& h, u16& l) {
  u16 hh = f2bf_rne(v);
  h = hh;
  l = f2bf_rne(v - bf2f(hh));
}

// ---------- global -> LDS async 16B ----------
__device__ __forceinline__ void gl16(const void* g, void* l) {
  __builtin_amdgcn_global_load_lds(
      (const __attribute__((address_space(1))) unsigned int*)g,
      (__attribute__((address_space(3))) unsigned int*)l,
      16, 0, 0);
}

// ---------- merged split-convert for all three inputs (vec4) ----------
__global__ void split_convert_all(const float4* __restrict__ x,
                                  ushort4* __restrict__ xhi, ushort4* __restrict__ xlo,
                                  const float4* __restrict__ wq,
                                  ushort4* __restrict__ wqh, ushort4* __restrict__ wql,
                                  const float4* __restrict__ wo,
                                  ushort4* __restrict__ woh, ushort4* __restrict__ wol) {
  int i = blockIdx.x * 256 + threadIdx.x;
  const float4* src;
  ushort4 *dh, *dl;
  int idx;
  if (i < 3145728) { src = x; dh = xhi; dl = xlo; idx = i; }
  else if (i < 3588096) { src = wq; dh = wqh; dl = wql; idx = i - 3145728; }
  else if (i < 3735552) { src = wo; dh = woh; dl = wol; idx = i - 3588096; }
  else return;
  float4 v = src[idx];
  ushort4 h, l;
  split1(v.x, h.x, l.x); split1(v.y, h.y, l.y);
  split1(v.z, h.z, l.z); split1(v.w, h.w, l.w);
  dh[idx] = h; dl[idx] = l;
}

// ---------- split-bf16 GEMM: C[M,N] = A[M,K] * B[N,K]^T (both K-major) ----------
// 128x128 tile, BK=64 (12 barriers instead of 24 -> halves vmcnt(0) drain cost),
// 4 waves (2x2), each wave 64x64 via 4x4 mfma_f32_16x16x32_bf16, 2 k-sub-blocks/iter.
// 3 MFMAs per fragment pair: hi*hi + hi*lo + lo*hi  (~2^-17 product error).
// LDS XOR swizzle (rows are 128 B = 8 x 16B chunks): physical chunk p of row r
// holds logical chunk p ^ (r&7). Every 8 consecutive reader lanes cover all 32
// banks exactly once -> conflict-free (R2 measured 0 conflicts with same scheme).
__global__ __launch_bounds__(256, 2) void gemm_split_bt(
    const u16* __restrict__ Ahi, const u16* __restrict__ Alo,
    const u16* __restrict__ Bhi, const u16* __restrict__ Blo,
    float* __restrict__ C, int M, int N, int K) {
  __shared__ __align__(16) u16 sAh[128 * 64], sAl[128 * 64], sBh[128 * 64], sBl[128 * 64];
  const int tid = threadIdx.x;
  const int wave = tid >> 6;
  const int lane = tid & 63;
  const int tm0 = blockIdx.x * 128;
  const int tn0 = blockIdx.y * 128;
  const int wm = (wave & 1) * 64;
  const int wn = (wave >> 1) * 64;

  // staging: per wave 4 gl16 per array; each covers 8 rows (128 B/row, 8 lanes/row)
  const int srow = wave * 32 + (lane >> 3);
  const int c = lane & 7;
  const int scol = (c ^ ((lane >> 3) & 7)) * 8;  // XOR-swizzled source chunk
  const u16* gAh = Ahi + (size_t)(tm0 + srow) * K + scol;
  const u16* gAl = Alo + (size_t)(tm0 + srow) * K + scol;
  const u16* gBh = Bhi + (size_t)(tn0 + srow) * K + scol;
  const u16* gBl = Blo + (size_t)(tn0 + srow) * K + scol;
  u16* lAh = &sAh[wave * 32 * 64];
  u16* lAl = &sAl[wave * 32 * 64];
  u16* lBh = &sBh[wave * 32 * 64];
  u16* lBl = &sBl[wave * 32 * 64];
  const size_t rstep8 = (size_t)8 * K;  // 8 rows per gl16

  f32x4 acc[4][4] = {};
  const int fr = lane & 15;    // A/B fragment row (m or n within 16-tile)
  const int quad = lane >> 4;  // logical k-chunk within 32-k sub-block

  for (int kt = 0; kt < K; kt += 64) {
#pragma unroll
    for (int r = 0; r < 4; ++r) {
      gl16(gAh + kt + r * rstep8, lAh + r * 512);
      gl16(gAl + kt + r * rstep8, lAl + r * 512);
      gl16(gBh + kt + r * rstep8, lBh + r * 512);
      gl16(gBl + kt + r * rstep8, lBl + r * 512);
    }
    __syncthreads();
    for (int subk = 0; subk < 2; ++subk) {
      const int k0 = ((subk * 4 + quad) ^ (fr & 7)) * 8;  // physical chunk * 8 u16
      bf16x8 ah[4], al[4], bh[4], bl[4];
#pragma unroll
      for (int i = 0; i < 4; ++i) {
        ah[i] = *(const bf16x8*)&sAh[(wm + i * 16 + fr) * 64 + k0];
        al[i] = *(const bf16x8*)&sAl[(wm + i * 16 + fr) * 64 + k0];
        bh[i] = *(const bf16x8*)&sBh[(wn + i * 16 + fr) * 64 + k0];
        bl[i] = *(const bf16x8*)&sBl[(wn + i * 16 + fr) * 64 + k0];
      }
#pragma unroll
      for (int i = 0; i < 4; ++i)
#pragma unroll
        for (int j = 0; j < 4; ++j) {
          acc[i][j] = __builtin_amdgcn_mfma_f32_16x16x32_bf16(ah[i], bh[j], acc[i][j], 0, 0, 0);
          acc[i][j] = __builtin_amdgcn_mfma_f32_16x16x32_bf16(ah[i], bl[j], acc[i][j], 0, 0, 0);
          acc[i][j] = __builtin_amdgcn_mfma_f32_16x16x32_bf16(al[i], bh[j], acc[i][j], 0, 0, 0);
        }
    }
    __syncthreads();
  }

  // C/D layout: col = lane&15, row = (lane>>4)*4 + reg  (verified m89/m91)
  const int col = lane & 15;
  const int rowq = (lane >> 4) * 4;
#pragma unroll
  for (int i = 0; i < 4; ++i)
#pragma unroll
    for (int j = 0; j < 4; ++j) {
      size_t base = (size_t)(tm0 + wm + i * 16 + rowq) * N + (tn0 + wn + j * 16 + col);
#pragma unroll
      for (int r = 0; r < 4; ++r) C[base + (size_t)r * N] = acc[i][j][r];
    }
}

// ---------- fused dilated attention ----------
// One block per (b, i0): tokens T_j = i0 + 2048*j, j=0..3. All 3 branches fold into
// a 4x4 combination matrix A per head: r=1 full softmax4; r=2 (i0 even) pair softmax2
// on (j, j^2); r=4 (i0%4==0) += identity.
__global__ __launch_bounds__(256) void attn_dilated(const float* __restrict__ qkv,
                                                    float* __restrict__ out) {
  __shared__ float rows[4][2304];   // [3][12][64] per token
  __shared__ float sc[12][16];
  __shared__ float Aw[12][16];
  const int t = threadIdx.x;
  const int i0 = blockIdx.x;  // 0..2047
  const int b = blockIdx.y;   // 0..1
  const size_t rowbase = (size_t)b * 8192 + i0;

  for (int idx = t; idx < 4 * 576; idx += 256) {
    int j = idx / 576, c4 = idx - j * 576;
    ((float4*)rows[j])[c4] = ((const float4*)(qkv + (rowbase + 2048 * j) * 2304))[c4];
  }
  __syncthreads();

  if (t < 192) {  // scores: q_j . k_jp / 8
    int h = t >> 4, j = (t >> 2) & 3, jp = t & 3;
    const float* q = &rows[j][h * 64];
    const float* k = &rows[jp][768 + h * 64];
    float s = 0.f;
#pragma unroll
    for (int d = 0; d < 64; ++d) s = fmaf(q[d], k[d], s);
    sc[h][(j << 2) | jp] = s * 0.125f;
  }
  __syncthreads();

  if (t < 48) {  // combine branch weights
    int h = t >> 2, j = t & 3;
    float s0 = sc[h][j * 4 + 0], s1 = sc[h][j * 4 + 1];
    float s2 = sc[h][j * 4 + 2], s3 = sc[h][j * 4 + 3];
    float m = fmaxf(fmaxf(s0, s1), fmaxf(s2, s3));
    float e0 = expf(s0 - m), e1 = expf(s1 - m), e2 = expf(s2 - m), e3 = expf(s3 - m);
    float inv = 1.f / (e0 + e1 + e2 + e3);
    float a[4] = {e0 * inv, e1 * inv, e2 * inv, e3 * inv};
    if ((i0 & 1) == 0) {
      int p = j ^ 2;
      float ss = sc[h][j * 4 + j], sx = sc[h][j * 4 + p];
      float mm = fmaxf(ss, sx);
      float es = expf(ss - mm), ex = expf(sx - mm);
      float iv = 1.f / (es + ex);
      a[j] += es * iv;
      a[p] += ex * iv;
    }
    if ((i0 & 3) == 0) a[j] += 1.f;
    Aw[h][j * 4 + 0] = a[0]; Aw[h][j * 4 + 1] = a[1];
    Aw[h][j * 4 + 2] = a[2]; Aw[h][j * 4 + 3] = a[3];
  }
  __syncthreads();

#pragma unroll
  for (int j = 0; j < 4; ++j) {
#pragma unroll
    for (int rep = 0; rep < 3; ++rep) {
      int cc = rep * 256 + t;  // 0..767
      int h = cc >> 6;
      float v = 0.f;
#pragma unroll
      for (int jp = 0; jp < 4; ++jp) v = fmaf(Aw[h][(j << 2) | jp], rows[jp][1536 + cc], v);
      out[(rowbase + 2048 * j) * 768 + cc] = v;
    }
  }
}

// ---------- column sums S[b,c] = sum_p out[b,p,c] ----------
__global__ void colsum(const float* __restrict__ o, float* __restrict__ S) {
  int t = threadIdx.x;
  int rg = blockIdx.x;  // 0..63 (128 rows each)
  int cg = blockIdx.y;  // 0..2
  int b = blockIdx.z;   // 0..1
  int c = cg * 256 + t;
  const float* p = o + ((size_t)b * 8192 + (size_t)rg * 128) * 768 + c;
  float s = 0.f;
  for (int r = 0; r < 128; ++r) s += p[(size_t)r * 768];
  atomicAdd(&S[b * 768 + c], s);
}

__global__ void invk(float* S, int n) {
  int i = blockIdx.x * 256 + threadIdx.x;
  if (i < n) S[i] = 1.0f / S[i];
}

// ---------- normalize by S and split-convert ----------
__global__ void norm_split4(const float4* __restrict__ in, const float* __restrict__ Sinv,
                            ushort4* __restrict__ hi, ushort4* __restrict__ lo, int n4) {
  int i = blockIdx.x * 256 + threadIdx.x;
  if (i >= n4) return;
  int e = i * 4;
  int c = e % 768;
  int b = e / (8192 * 768);
  const float* s = Sinv + b * 768 + c;
  float4 v = in[i];
  v.x *= s[0]; v.y *= s[1]; v.z *= s[2]; v.w *= s[3];
  ushort4 h, l;
  split1(v.x, h.x, l.x); split1(v.y, h.y, l.y);
  split1(v.z, h.z, l.z); split1(v.w, h.w, l.w);
  hi[i] = h; lo[i] = l;
}

extern "C" void kernel_launch(void* const* d_in, const int* in_sizes, int n_in,
                              void* d_out, int out_size, void* d_ws, size_t ws_size,
                              hipStream_t stream) {
  (void)in_sizes; (void)n_in; (void)out_size; (void)ws_size;
  const float* x = (const float*)d_in[0];     // (2,8192,768)
  const float* Wqkv = (const float*)d_in[1];  // (2304,768)
  const float* Wout = (const float*)d_in[2];  // (768,768)
  float* out = (float*)d_out;                 // (2,8192,768) fp32; also attn scratch

  // workspace layout (bytes). qkv region is reused for no_hi/no_lo after attention.
  char* w = (char*)d_ws;
  float* qkv = (float*)(w);                    // 150,994,944
  u16* no_hi = (u16*)(w);                      // 25,165,824 (reuse)
  u16* no_lo = (u16*)(w + 25165824);           // 25,165,824 (reuse)
  size_t off = 150994944;
  u16* xhi = (u16*)(w + off); off += 25165824;
  u16* xlo = (u16*)(w + off); off += 25165824;
  u16* wqh = (u16*)(w + off); off += 3538944;
  u16* wql = (u16*)(w + off); off += 3538944;
  u16* woh = (u16*)(w + off); off += 1179648;
  u16* wol = (u16*)(w + off); off += 1179648;
  float* S = (float*)(w + off); off += 6144;   // ~201 MB total

  // 1) split-convert all inputs (one launch)
  split_convert_all<<<dim3(14592), 256, 0, stream>>>(
      (const float4*)x, (ushort4*)xhi, (ushort4*)xlo,
      (const float4*)Wqkv, (ushort4*)wqh, (ushort4*)wql,
      (const float4*)Wout, (ushort4*)woh, (ushort4*)wol);

  // 2) qkv = x @ Wqkv^T   (M=16384, N=2304, K=768)
  gemm_split_bt<<<dim3(128, 18), 256, 0, stream>>>(xhi, xlo, wqh, wql, qkv, 16384, 2304, 768);

  // 3) dilated attention -> out (d_out as scratch)
  attn_dilated<<<dim3(2048, 2), 256, 0, stream>>>(qkv, out);

  // 4) S = column sums over n; then invert
  hipMemsetAsync(S, 0, 6144, stream);
  colsum<<<dim3(64, 3, 2), 256, 0, stream>>>(out, S);
  invk<<<dim3(6), 256, 0, stream>>>(S, 1536);

  // 5) normalize + split-convert (reuses qkv region)
  norm_split4<<<dim3((3145728 + 255) / 256), 256, 0, stream>>>(
      (const float4*)out, S, (ushort4*)no_hi, (ushort4*)no_lo, 3145728);

  // 6) out = no @ Wout^T   (M=16384, N=768, K=768)
  gemm_split_bt<<<dim3(128, 6), 256, 0, stream>>>(no_hi, no_lo, woh, wol, out, 16384, 768, 768);
}